// Round 1
// baseline (76.271 us; speedup 1.0000x reference)
//
#include <hip/hip_runtime.h>

// Gaussian splat renderer: B=2, 9 params x 32x32 gaussians -> [B,3,128,128] image.
// Kernel 1: per-gaussian preprocessing (mu, Sigma^-1 folded into exp2-scaled
//           quadratic coeffs, opacity-premultiplied colors) -> d_ws.
// Kernel 2: per-pixel accumulation over all 1024 gaussians, split 8-way across
//           blockDim.y for occupancy, LDS-broadcast gaussian table, LDS reduce.

#define NB   2
#define NG   1024            // gaussians per batch (32*32)
#define HOUT 128
#define WOUT 128
#define GSTRIDE 12           // floats per gaussian record (9 used + pad to 48B)

__global__ __launch_bounds__(256) void gauss_setup(const float* __restrict__ params,
                                                   float* __restrict__ gd) {
    int gid = blockIdx.x * blockDim.x + threadIdx.x;
    if (gid >= NB * NG) return;
    int b = gid >> 10;
    int n = gid & (NG - 1);
    int h = n >> 5;
    int w = n & 31;

    const float* P = params + b * 9 * NG + n;   // channel stride = 1024
    float p0 = P[0 * NG];
    float p1 = P[1 * NG];
    float p2 = P[2 * NG];
    float p3 = P[3 * NG];
    float p4 = P[4 * NG];
    float p5 = P[5 * NG];
    float p6 = P[6 * NG];
    float p7 = P[7 * NG];
    float p8 = P[8 * NG];

    // base_grid: linspace(-31/32, 31/32, 32) -> -0.96875 + i/16; offset scale 2/32
    float mux = -0.96875f + (float)w * 0.0625f + tanhf(p0) * 0.0625f;
    float muy = -0.96875f + (float)h * 0.0625f + tanhf(p1) * 0.0625f;

    // cov = L L^T + 1e-5 I,  L = [[e^a,0],[b,e^c]]
    float ea  = expf(p2);
    float ec  = expf(p4);
    float c00 = ea * ea + 1e-5f;
    float c01 = p3 * ea;
    float c11 = p3 * p3 + ec * ec + 1e-5f;
    float det = c00 * c11 - c01 * c01;
    float id  = 1.0f / det;
    float Sa  =  c11 * id;      // Sinv00
    float Sb  = -c01 * id;      // Sinv01
    float Sc  =  c00 * id;      // Sinv11

    // exponent = -0.5 * (Sa dx^2 + 2 Sb dx dy + Sc dy^2); fold -0.5*log2(e)
    // so the render loop computes exp2 directly.
    const float s = -0.72134752044448169f;   // -0.5 * log2(e)
    float A  = s * Sa;
    float B2 = 2.0f * s * Sb;
    float C  = s * Sc;

    float cr = 1.0f / (1.0f + expf(-p5));
    float cg = 1.0f / (1.0f + expf(-p6));
    float cb = 1.0f / (1.0f + expf(-p7));
    float op = 1.0f / (1.0f + expf(-p8));

    float* o = gd + gid * GSTRIDE;
    o[0]  = mux;  o[1]  = muy;  o[2]  = A;       o[3]  = B2;
    o[4]  = C;    o[5]  = op;   o[6]  = op * cr; o[7]  = op * cg;
    o[8]  = op * cb; o[9] = 0.0f; o[10] = 0.0f; o[11] = 0.0f;
}

// blockDim = (64 pixels, 8 chunks). 256 blocks per batch (16384 px / 64).
__global__ __launch_bounds__(512, 2) void gauss_render(const float* __restrict__ gd,
                                                       float* __restrict__ out) {
    __shared__ float  sg[NG * GSTRIDE];      // 48 KB gaussian table
    __shared__ float4 sred[512];             // 8 KB partial reduce

    const int tx  = threadIdx.x;             // pixel lane   [0,64)
    const int ty  = threadIdx.y;             // chunk        [0,8)
    const int tid = ty * 64 + tx;
    const int blk = blockIdx.x;
    const int b   = blk >> 8;                       // batch
    const int pix = ((blk & 255) << 6) + tx;        // pixel in [0,16384)

    // ---- stage gaussian table for this batch into LDS (float4 copies) ----
    const float4* src = (const float4*)(gd + b * NG * GSTRIDE);
    float4* dst = (float4*)sg;
    #pragma unroll
    for (int i = tid; i < NG * GSTRIDE / 4; i += 512) dst[i] = src[i];
    __syncthreads();

    const int h = pix >> 7;
    const int w = pix & 127;
    const float px = -1.0f + (float)w * (2.0f / 127.0f);
    const float py = -1.0f + (float)h * (2.0f / 127.0f);

    float wsum = 0.0f, ar = 0.0f, ag = 0.0f, ab = 0.0f;

    const float* gp = sg + ty * (NG / 8) * GSTRIDE;
    #pragma unroll 4
    for (int j = 0; j < NG / 8; ++j) {
        const float4* q4 = (const float4*)(gp + j * GSTRIDE);
        float4 q0 = q4[0];                   // mux, muy, A, B2
        float4 q1 = q4[1];                   // C, op, ocr, ocg
        float  q2 = ((const float*)q4)[8];   // ocb

        float dx = px - q0.x;
        float dy = py - q0.y;
        // e2 = A dx^2 + B2 dx dy + C dy^2   (already exp2-scaled, <= 0)
        float m1 = q0.z * dx;
        float m2 = q0.w * dx;
        float m3 = q1.x * dy;
        float e2 = fmaf(m1, dx, fmaf(m2, dy, m3 * dy));
        e2 = fmaxf(e2, -28.853900817779268f);   // clip exponent at -20 (ln)
        float k = __builtin_amdgcn_exp2f(e2);

        wsum = fmaf(q1.y, k, wsum);
        ar   = fmaf(q1.z, k, ar);
        ag   = fmaf(q1.w, k, ag);
        ab   = fmaf(q2,   k, ab);
    }

    sred[tid] = make_float4(wsum, ar, ag, ab);
    __syncthreads();

    if (ty == 0) {
        float4 a = sred[tx];
        #pragma unroll
        for (int k2 = 1; k2 < 8; ++k2) {
            float4 t = sred[k2 * 64 + tx];
            a.x += t.x; a.y += t.y; a.z += t.z; a.w += t.w;
        }
        float inv = 1.0f / (a.x + 1e-8f);
        float* ob = out + b * 3 * (HOUT * WOUT) + pix;
        ob[0]                 = a.y * inv;
        ob[HOUT * WOUT]       = a.z * inv;
        ob[2 * HOUT * WOUT]   = a.w * inv;
    }
}

extern "C" void kernel_launch(void* const* d_in, const int* in_sizes, int n_in,
                              void* d_out, int out_size, void* d_ws, size_t ws_size,
                              hipStream_t stream) {
    const float* params = (const float*)d_in[0];
    float* gd  = (float*)d_ws;          // 2048 * 12 * 4 B = 96 KB scratch
    float* out = (float*)d_out;

    hipLaunchKernelGGL(gauss_setup, dim3((NB * NG + 255) / 256), dim3(256), 0, stream,
                       params, gd);
    hipLaunchKernelGGL(gauss_render, dim3(NB * (HOUT * WOUT) / 64), dim3(64, 8), 0,
                       stream, gd, out);
}

// Round 2
// 74.517 us; speedup vs baseline: 1.0235x; 1.0235x over previous
//
#include <hip/hip_runtime.h>

// Gaussian splat renderer: B=2, 9 params x 32x32 gaussians -> [B,3,128,128].
// Kernel 1: per-gaussian preprocessing (mu, Sigma^-1 folded into exp2-scaled
//           quadratic coeffs, opacity-premultiplied colors) -> d_ws.
// Kernel 2: per-pixel accumulation. Gaussian records are read via WAVE-UNIFORM
//           scalar loads (readfirstlane-forced) -> s_load into SGPRs, zero
//           in-loop LDS traffic. LDS only for the 8-chunk partial reduce.

#define NB   2
#define NG   1024            // gaussians per batch (32*32)
#define HOUT 128
#define WOUT 128
#define GSTRIDE 12           // floats per gaussian record (9 used + pad to 48B)

__global__ __launch_bounds__(256) void gauss_setup(const float* __restrict__ params,
                                                   float* __restrict__ gd) {
    int gid = blockIdx.x * blockDim.x + threadIdx.x;
    if (gid >= NB * NG) return;
    int b = gid >> 10;
    int n = gid & (NG - 1);
    int h = n >> 5;
    int w = n & 31;

    const float* P = params + b * 9 * NG + n;   // channel stride = 1024
    float p0 = P[0 * NG];
    float p1 = P[1 * NG];
    float p2 = P[2 * NG];
    float p3 = P[3 * NG];
    float p4 = P[4 * NG];
    float p5 = P[5 * NG];
    float p6 = P[6 * NG];
    float p7 = P[7 * NG];
    float p8 = P[8 * NG];

    // base_grid: linspace(-31/32, 31/32, 32) -> -0.96875 + i/16; offset scale 2/32
    float mux = -0.96875f + (float)w * 0.0625f + tanhf(p0) * 0.0625f;
    float muy = -0.96875f + (float)h * 0.0625f + tanhf(p1) * 0.0625f;

    // cov = L L^T + 1e-5 I,  L = [[e^a,0],[b,e^c]]
    float ea  = expf(p2);
    float ec  = expf(p4);
    float c00 = ea * ea + 1e-5f;
    float c01 = p3 * ea;
    float c11 = p3 * p3 + ec * ec + 1e-5f;
    float det = c00 * c11 - c01 * c01;
    float id  = 1.0f / det;
    float Sa  =  c11 * id;      // Sinv00
    float Sb  = -c01 * id;      // Sinv01
    float Sc  =  c00 * id;      // Sinv11

    // exponent = -0.5*(Sa dx^2 + 2 Sb dx dy + Sc dy^2); fold -0.5*log2(e) so
    // the render loop computes exp2 directly.
    const float s = -0.72134752044448169f;   // -0.5 * log2(e)
    float A  = s * Sa;
    float B2 = 2.0f * s * Sb;
    float C  = s * Sc;

    float cr = 1.0f / (1.0f + expf(-p5));
    float cg = 1.0f / (1.0f + expf(-p6));
    float cb = 1.0f / (1.0f + expf(-p7));
    float op = 1.0f / (1.0f + expf(-p8));

    float* o = gd + gid * GSTRIDE;
    o[0]  = mux;  o[1]  = muy;  o[2]  = A;       o[3]  = B2;
    o[4]  = C;    o[5]  = op;   o[6]  = op * cr; o[7]  = op * cg;
    o[8]  = op * cb; o[9] = 0.0f; o[10] = 0.0f; o[11] = 0.0f;
}

// blockDim = (64 pixels, 8 chunks). 256 blocks per batch (16384 px / 64).
__global__ __launch_bounds__(512) void gauss_render(const float* __restrict__ gd,
                                                    float* __restrict__ out) {
    __shared__ float4 sred[512];             // 8 KB partial reduce only

    const int tx  = threadIdx.x;             // pixel lane   [0,64)
    const int ty  = threadIdx.y;             // chunk        [0,8)
    const int tid = ty * 64 + tx;
    const int blk = blockIdx.x;
    const int b   = blk >> 8;                       // batch
    const int pix = ((blk & 255) << 6) + tx;        // pixel in [0,16384)

    const int h = pix >> 7;
    const int w = pix & 127;
    const float px = -1.0f + (float)w * (2.0f / 127.0f);
    const float py = -1.0f + (float)h * (2.0f / 127.0f);

    // Wave-uniform chunk base: force into SGPR so the record loads become
    // s_load_dwordx* on the scalar pipe (broadcast for free, no LDS/VMEM).
    const int chunk = __builtin_amdgcn_readfirstlane(ty);
    const float* __restrict__ gp =
        gd + (size_t)b * NG * GSTRIDE + (size_t)chunk * (NG / 8) * GSTRIDE;

    float wsum = 0.0f, ar = 0.0f, ag = 0.0f, ab = 0.0f;

    #pragma unroll 4
    for (int j = 0; j < NG / 8; ++j) {
        const float* __restrict__ r = gp + j * GSTRIDE;
        const float mux = r[0], muy = r[1];
        const float A   = r[2], B2  = r[3], C = r[4];
        const float op  = r[5], ocr = r[6], ocg = r[7], ocb = r[8];

        float dx = px - mux;
        float dy = py - muy;
        // e2 = A dx^2 + B2 dx dy + C dy^2   (already exp2-scaled, <= 0)
        float m  = A * dx;
        m        = fmaf(B2, dy, m);
        float e2 = fmaf(C * dy, dy, m * dx);
        e2 = fmaxf(e2, -28.853900817779268f);   // clip exponent at -20 (ln)
        float k = __builtin_amdgcn_exp2f(e2);

        wsum = fmaf(op,  k, wsum);
        ar   = fmaf(ocr, k, ar);
        ag   = fmaf(ocg, k, ag);
        ab   = fmaf(ocb, k, ab);
    }

    sred[tid] = make_float4(wsum, ar, ag, ab);
    __syncthreads();

    if (ty == 0) {
        float4 a = sred[tx];
        #pragma unroll
        for (int k2 = 1; k2 < 8; ++k2) {
            float4 t = sred[k2 * 64 + tx];
            a.x += t.x; a.y += t.y; a.z += t.z; a.w += t.w;
        }
        float inv = 1.0f / (a.x + 1e-8f);
        float* ob = out + b * 3 * (HOUT * WOUT) + pix;
        ob[0]                 = a.y * inv;
        ob[HOUT * WOUT]       = a.z * inv;
        ob[2 * HOUT * WOUT]   = a.w * inv;
    }
}

extern "C" void kernel_launch(void* const* d_in, const int* in_sizes, int n_in,
                              void* d_out, int out_size, void* d_ws, size_t ws_size,
                              hipStream_t stream) {
    const float* params = (const float*)d_in[0];
    float* gd  = (float*)d_ws;          // 2048 * 12 * 4 B = 96 KB scratch
    float* out = (float*)d_out;

    hipLaunchKernelGGL(gauss_setup, dim3((NB * NG + 255) / 256), dim3(256), 0, stream,
                       params, gd);
    hipLaunchKernelGGL(gauss_render, dim3(NB * (HOUT * WOUT) / 64), dim3(64, 8), 0,
                       stream, gd, out);
}

// Round 3
// 71.059 us; speedup vs baseline: 1.0733x; 1.0487x over previous
//
#include <hip/hip_runtime.h>

// Gaussian splat renderer: B=2, 9 params x 32x32 gaussians -> [B,3,128,128].
// Kernel 1: per-gaussian preprocessing into PAIR-BLOCKED records (fields of
//           gaussians 2j,2j+1 adjacent) so the render loop can use packed
//           dual-FP32 (v_pk_fma_f32) with SGPR-pair constants.
// Kernel 2: per-pixel accumulation, 16-way gaussian-chunk split (32 waves/CU),
//           wave-uniform s_load records, packed f32 math, LDS reduce.

#define NB   2
#define NG   1024            // gaussians per batch (32*32)
#define HOUT 128
#define WOUT 128
#define PSTRIDE 24           // floats per gaussian-PAIR record (18 used + pad)
#define NCHUNK 16

typedef float v2f __attribute__((ext_vector_type(2)));

__global__ __launch_bounds__(256) void gauss_setup(const float* __restrict__ params,
                                                   float* __restrict__ gd) {
    int gid = blockIdx.x * blockDim.x + threadIdx.x;
    if (gid >= NB * NG) return;
    int b = gid >> 10;
    int n = gid & (NG - 1);
    int h = n >> 5;
    int w = n & 31;

    const float* P = params + b * 9 * NG + n;   // channel stride = 1024
    float p0 = P[0 * NG];
    float p1 = P[1 * NG];
    float p2 = P[2 * NG];
    float p3 = P[3 * NG];
    float p4 = P[4 * NG];
    float p5 = P[5 * NG];
    float p6 = P[6 * NG];
    float p7 = P[7 * NG];
    float p8 = P[8 * NG];

    // base_grid: linspace(-31/32, 31/32, 32) -> -0.96875 + i/16; offset scale 2/32
    float mux = -0.96875f + (float)w * 0.0625f + tanhf(p0) * 0.0625f;
    float muy = -0.96875f + (float)h * 0.0625f + tanhf(p1) * 0.0625f;

    // cov = L L^T + 1e-5 I,  L = [[e^a,0],[b,e^c]]
    float ea  = expf(p2);
    float ec  = expf(p4);
    float c00 = ea * ea + 1e-5f;
    float c01 = p3 * ea;
    float c11 = p3 * p3 + ec * ec + 1e-5f;
    float det = c00 * c11 - c01 * c01;
    float id  = 1.0f / det;
    float Sa  =  c11 * id;      // Sinv00
    float Sb  = -c01 * id;      // Sinv01
    float Sc  =  c00 * id;      // Sinv11

    // exponent = -0.5*(Sa dx^2 + 2 Sb dx dy + Sc dy^2); fold -0.5*log2(e) so
    // the render loop computes exp2 directly.
    const float s = -0.72134752044448169f;   // -0.5 * log2(e)
    float A  = s * Sa;
    float B2 = 2.0f * s * Sb;
    float C  = s * Sc;

    float cr = 1.0f / (1.0f + expf(-p5));
    float cg = 1.0f / (1.0f + expf(-p6));
    float cb = 1.0f / (1.0f + expf(-p7));
    float op = 1.0f / (1.0f + expf(-p8));

    // pair-blocked layout: record for pair (n>>1), half (n&1); field stride 2
    float* o = gd + ((size_t)b * (NG / 2) + (n >> 1)) * PSTRIDE + (n & 1);
    o[0]  = mux;  o[2]  = muy;  o[4]  = A;       o[6]  = B2;
    o[8]  = C;    o[10] = op;   o[12] = op * cr; o[14] = op * cg;
    o[16] = op * cb;
}

// blockDim = (64 pixels, 16 chunks). 256 blocks per batch (16384 px / 64).
__global__ __launch_bounds__(1024, 8) void gauss_render(const float* __restrict__ gd,
                                                        float* __restrict__ out) {
    __shared__ float4 sred[1024];            // 16 KB partial reduce

    const int tx  = threadIdx.x;             // pixel lane   [0,64)
    const int ty  = threadIdx.y;             // chunk        [0,16)
    const int tid = ty * 64 + tx;
    const int blk = blockIdx.x;
    const int b   = blk >> 8;                       // batch
    const int pix = ((blk & 255) << 6) + tx;        // pixel in [0,16384)

    const int h = pix >> 7;
    const int w = pix & 127;
    const float px = -1.0f + (float)w * (2.0f / 127.0f);
    const float py = -1.0f + (float)h * (2.0f / 127.0f);
    const v2f px2 = {px, px};
    const v2f py2 = {py, py};

    // Wave-uniform chunk base -> s_load records into SGPRs (free broadcast).
    const int chunk = __builtin_amdgcn_readfirstlane(ty);
    const v2f* __restrict__ gp = (const v2f*)(gd
        + (size_t)b * (NG / 2) * PSTRIDE
        + (size_t)chunk * (NG / 2 / NCHUNK) * PSTRIDE);

    v2f wsum2 = {0.0f, 0.0f}, ar2 = {0.0f, 0.0f};
    v2f ag2   = {0.0f, 0.0f}, ab2 = {0.0f, 0.0f};

    #pragma unroll 2
    for (int j = 0; j < NG / 2 / NCHUNK; ++j) {     // 32 pair-iterations
        const v2f* __restrict__ r = gp + j * (PSTRIDE / 2);
        v2f mux2 = r[0], muy2 = r[1];
        v2f A2   = r[2], B22  = r[3], C2 = r[4];
        v2f op2  = r[5], ocr2 = r[6], ocg2 = r[7], ocb2 = r[8];

        v2f dx = px2 - mux2;
        v2f dy = py2 - muy2;
        // e2 = A dx^2 + B2 dx dy + C dy^2   (exp2-scaled, <= 0)
        v2f m  = A2 * dx;
        m      = __builtin_elementwise_fma(B22, dy, m);
        v2f t  = C2 * dy;
        v2f e2 = __builtin_elementwise_fma(t, dy, m * dx);
        e2 = __builtin_elementwise_max(e2, (v2f){-28.853900817779268f,
                                                 -28.853900817779268f});
        v2f k2 = {__builtin_amdgcn_exp2f(e2.x), __builtin_amdgcn_exp2f(e2.y)};

        wsum2 = __builtin_elementwise_fma(op2,  k2, wsum2);
        ar2   = __builtin_elementwise_fma(ocr2, k2, ar2);
        ag2   = __builtin_elementwise_fma(ocg2, k2, ag2);
        ab2   = __builtin_elementwise_fma(ocb2, k2, ab2);
    }

    sred[tid] = make_float4(wsum2.x + wsum2.y, ar2.x + ar2.y,
                            ag2.x + ag2.y,     ab2.x + ab2.y);
    __syncthreads();

    if (ty == 0) {
        float4 a = sred[tx];
        #pragma unroll
        for (int k2i = 1; k2i < NCHUNK; ++k2i) {
            float4 t = sred[k2i * 64 + tx];
            a.x += t.x; a.y += t.y; a.z += t.z; a.w += t.w;
        }
        float inv = 1.0f / (a.x + 1e-8f);
        float* ob = out + b * 3 * (HOUT * WOUT) + pix;
        ob[0]               = a.y * inv;
        ob[HOUT * WOUT]     = a.z * inv;
        ob[2 * HOUT * WOUT] = a.w * inv;
    }
}

extern "C" void kernel_launch(void* const* d_in, const int* in_sizes, int n_in,
                              void* d_out, int out_size, void* d_ws, size_t ws_size,
                              hipStream_t stream) {
    const float* params = (const float*)d_in[0];
    float* gd  = (float*)d_ws;          // 2 * 512 * 24 * 4 B = 96 KB scratch
    float* out = (float*)d_out;

    hipLaunchKernelGGL(gauss_setup, dim3((NB * NG + 255) / 256), dim3(256), 0, stream,
                       params, gd);
    hipLaunchKernelGGL(gauss_render, dim3(NB * (HOUT * WOUT) / 64), dim3(64, 16), 0,
                       stream, gd, out);
}

// Round 4
// 69.646 us; speedup vs baseline: 1.0951x; 1.0203x over previous
//
#include <hip/hip_runtime.h>

// Gaussian splat renderer: B=2, 9 params x 32x32 gaussians -> [B,3,128,128].
// Kernel 1: per-gaussian preprocessing into PAIR-BLOCKED records (fields of
//           gaussians 2j,2j+1 adjacent) -> packed dual-FP32 render math.
//           Transcendentals via inline exp2/rcp (no ocml calls).
// Kernel 2: per-pixel accumulation, 16-way gaussian-chunk split, wave-uniform
//           s_load records (scalar pipe, free broadcast), packed f32 math,
//           LDS reduce. Two-kernel split is deliberate: table reads ride the
//           SMEM pipe; fusing would force them onto the LDS pipe (~2x worse).

#define NB   2
#define NG   1024            // gaussians per batch (32*32)
#define HOUT 128
#define WOUT 128
#define PSTRIDE 24           // floats per gaussian-PAIR record (18 used + pad)
#define NCHUNK 16

typedef float v2f __attribute__((ext_vector_type(2)));

__device__ __forceinline__ float fast_exp(float x) {
    // e^x = 2^(x*log2e); range here is moderate (params ~N(0,1))
    return __builtin_amdgcn_exp2f(x * 1.4426950408889634f);
}
__device__ __forceinline__ float fast_sigmoid(float x) {
    float e = __builtin_amdgcn_exp2f(-x * 1.4426950408889634f);
    return __builtin_amdgcn_rcpf(1.0f + e);
}
__device__ __forceinline__ float fast_tanh(float x) {
    // tanh(x) = 2*sigmoid(2x) - 1
    float e = __builtin_amdgcn_exp2f(-x * 2.8853900817779268f);
    return fmaf(2.0f, __builtin_amdgcn_rcpf(1.0f + e), -1.0f);
}

__global__ __launch_bounds__(256) void gauss_setup(const float* __restrict__ params,
                                                   float* __restrict__ gd) {
    int gid = blockIdx.x * blockDim.x + threadIdx.x;
    if (gid >= NB * NG) return;
    int b = gid >> 10;
    int n = gid & (NG - 1);
    int h = n >> 5;
    int w = n & 31;

    const float* P = params + b * 9 * NG + n;   // channel stride = 1024
    float p0 = P[0 * NG];
    float p1 = P[1 * NG];
    float p2 = P[2 * NG];
    float p3 = P[3 * NG];
    float p4 = P[4 * NG];
    float p5 = P[5 * NG];
    float p6 = P[6 * NG];
    float p7 = P[7 * NG];
    float p8 = P[8 * NG];

    // base_grid: linspace(-31/32, 31/32, 32) -> -0.96875 + i/16; offset 2/32
    float mux = -0.96875f + (float)w * 0.0625f + fast_tanh(p0) * 0.0625f;
    float muy = -0.96875f + (float)h * 0.0625f + fast_tanh(p1) * 0.0625f;

    // cov = L L^T + 1e-5 I,  L = [[e^a,0],[b,e^c]]
    float ea  = fast_exp(p2);
    float ec  = fast_exp(p4);
    float c00 = ea * ea + 1e-5f;
    float c01 = p3 * ea;
    float c11 = p3 * p3 + ec * ec + 1e-5f;
    float det = c00 * c11 - c01 * c01;
    float id  = 1.0f / det;            // exact divide: det can be ~1e-10
    float Sa  =  c11 * id;
    float Sb  = -c01 * id;
    float Sc  =  c00 * id;

    // exponent = -0.5*(Sa dx^2 + 2 Sb dx dy + Sc dy^2); fold -0.5*log2(e) so
    // the render loop computes exp2 directly.
    const float s = -0.72134752044448169f;   // -0.5 * log2(e)
    float A  = s * Sa;
    float B2 = 2.0f * s * Sb;
    float C  = s * Sc;

    float cr = fast_sigmoid(p5);
    float cg = fast_sigmoid(p6);
    float cb = fast_sigmoid(p7);
    float op = fast_sigmoid(p8);

    // pair-blocked layout: record for pair (n>>1), half (n&1); field stride 2
    float* o = gd + ((size_t)b * (NG / 2) + (n >> 1)) * PSTRIDE + (n & 1);
    o[0]  = mux;  o[2]  = muy;  o[4]  = A;       o[6]  = B2;
    o[8]  = C;    o[10] = op;   o[12] = op * cr; o[14] = op * cg;
    o[16] = op * cb;
}

// blockDim = (64 pixels, 16 chunks). 256 blocks per batch (16384 px / 64).
__global__ __launch_bounds__(1024, 8) void gauss_render(const float* __restrict__ gd,
                                                        float* __restrict__ out) {
    __shared__ float4 sred[1024];            // 16 KB partial reduce

    const int tx  = threadIdx.x;             // pixel lane   [0,64)
    const int ty  = threadIdx.y;             // chunk        [0,16)
    const int tid = ty * 64 + tx;
    const int blk = blockIdx.x;
    const int b   = blk >> 8;                       // batch
    const int pix = ((blk & 255) << 6) + tx;        // pixel in [0,16384)

    const int h = pix >> 7;
    const int w = pix & 127;
    const float px = -1.0f + (float)w * (2.0f / 127.0f);
    const float py = -1.0f + (float)h * (2.0f / 127.0f);
    const v2f px2 = {px, px};
    const v2f py2 = {py, py};

    // Wave-uniform chunk base -> s_load records into SGPRs (free broadcast).
    const int chunk = __builtin_amdgcn_readfirstlane(ty);
    const v2f* __restrict__ gp = (const v2f*)(gd
        + (size_t)b * (NG / 2) * PSTRIDE
        + (size_t)chunk * (NG / 2 / NCHUNK) * PSTRIDE);

    v2f wsum2 = {0.0f, 0.0f}, ar2 = {0.0f, 0.0f};
    v2f ag2   = {0.0f, 0.0f}, ab2 = {0.0f, 0.0f};

    #pragma unroll 4
    for (int j = 0; j < NG / 2 / NCHUNK; ++j) {     // 32 pair-iterations
        const v2f* __restrict__ r = gp + j * (PSTRIDE / 2);
        v2f mux2 = r[0], muy2 = r[1];
        v2f A2   = r[2], B22  = r[3], C2 = r[4];
        v2f op2  = r[5], ocr2 = r[6], ocg2 = r[7], ocb2 = r[8];

        v2f dx = px2 - mux2;
        v2f dy = py2 - muy2;
        // e2 = A dx^2 + B2 dx dy + C dy^2   (exp2-scaled, <= 0)
        v2f m  = A2 * dx;
        m      = __builtin_elementwise_fma(B22, dy, m);
        v2f t  = C2 * dy;
        v2f e2 = __builtin_elementwise_fma(t, dy, m * dx);
        e2 = __builtin_elementwise_max(e2, (v2f){-28.853900817779268f,
                                                 -28.853900817779268f});
        v2f k2 = {__builtin_amdgcn_exp2f(e2.x), __builtin_amdgcn_exp2f(e2.y)};

        wsum2 = __builtin_elementwise_fma(op2,  k2, wsum2);
        ar2   = __builtin_elementwise_fma(ocr2, k2, ar2);
        ag2   = __builtin_elementwise_fma(ocg2, k2, ag2);
        ab2   = __builtin_elementwise_fma(ocb2, k2, ab2);
    }

    sred[tid] = make_float4(wsum2.x + wsum2.y, ar2.x + ar2.y,
                            ag2.x + ag2.y,     ab2.x + ab2.y);
    __syncthreads();

    if (ty == 0) {
        float4 a = sred[tx];
        #pragma unroll
        for (int k2i = 1; k2i < NCHUNK; ++k2i) {
            float4 t = sred[k2i * 64 + tx];
            a.x += t.x; a.y += t.y; a.z += t.z; a.w += t.w;
        }
        float inv = 1.0f / (a.x + 1e-8f);
        float* ob = out + b * 3 * (HOUT * WOUT) + pix;
        ob[0]               = a.y * inv;
        ob[HOUT * WOUT]     = a.z * inv;
        ob[2 * HOUT * WOUT] = a.w * inv;
    }
}

extern "C" void kernel_launch(void* const* d_in, const int* in_sizes, int n_in,
                              void* d_out, int out_size, void* d_ws, size_t ws_size,
                              hipStream_t stream) {
    const float* params = (const float*)d_in[0];
    float* gd  = (float*)d_ws;          // 2 * 512 * 24 * 4 B = 96 KB scratch
    float* out = (float*)d_out;

    hipLaunchKernelGGL(gauss_setup, dim3((NB * NG + 255) / 256), dim3(256), 0, stream,
                       params, gd);
    hipLaunchKernelGGL(gauss_render, dim3(NB * (HOUT * WOUT) / 64), dim3(64, 16), 0,
                       stream, gd, out);
}